// Round 5
// baseline (1837.018 us; speedup 1.0000x reference)
//
#include <hip/hip_runtime.h>
#include <math.h>

// GCN generator: B=8, N=F=128. One block/batch, 1024 threads (16 waves).
// Round 5: G carried in REGISTERS as MFMA A-fragments (4x wc-redundant);
// z = G(x.W) re-association kills the y-transpose; 4 barriers/step.
// P1: G-update(regs)+rowsums+row-dump || mm_a u=x.W -> U[fo][m]
// P2: mm_b z=G.u + relu/ssq/zrow   P3: normalize->X[n][f], pd
// P4 (wave0): probs, degrees, d, s_gi (next row/col), out writes.

#define NN 128
#define SP 136

typedef _Float16 f16;
typedef _Float16 f16x8 __attribute__((ext_vector_type(8)));
typedef _Float16 f16x4 __attribute__((ext_vector_type(4)));
typedef _Float16 f16x2 __attribute__((ext_vector_type(2)));
typedef float f32x4 __attribute__((ext_vector_type(4)));

__device__ __forceinline__ f32x4 mm(f16x8 a, f16x8 b, f32x4 c) {
    return __builtin_amdgcn_mfma_f32_16x16x32_f16(a, b, c, 0, 0, 0);
}

__device__ __forceinline__ float rowdot8(f16x8 g, float acc) {
#if __has_builtin(__builtin_amdgcn_fdot2)
    const f16x2 one2 = {(f16)1.0f, (f16)1.0f};
    #pragma unroll
    for (int p = 0; p < 4; ++p) {
        f16x2 pr = {g[2*p], g[2*p+1]};
        acc = __builtin_amdgcn_fdot2(pr, one2, acc, false);
    }
#else
    #pragma unroll
    for (int e = 0; e < 8; ++e) acc += (float)g[e];
#endif
    return acc;
}

__global__ __launch_bounds__(1024, 4)
void gcn_gen_kernel(const float* __restrict__ gx,
                    const float* __restrict__ gW,
                    const float* __restrict__ gb,
                    float* __restrict__ gout)
{
    extern __shared__ char lds_raw[];
    f16* X      = (f16*)lds_raw;            // [128][136] x-hat, row-major [n][f]
    f16* U      = X + NN*SP;                // [128][136] u = x.W, stored [fo][m]
    f16* s_df16 = U + NN*SP;                // [128] d (f16)
    f16* s_gi   = s_df16 + NN;              // [128] final new G row/col i
    f16* s_rowi = s_gi + NN;                // [128] G_i row piv (dump)
    float* s_rows = (float*)(s_rowi + NN);  // [128] rowsum(G_i)
    float* s_ssq  = s_rows + NN;            // [4][128] ssq partials by wc
    float* s_pdt  = s_ssq + 4*NN;           // [4][128] zdot partials by wc
    float* s_zrow = s_pdt + 4*NN;           // [128] pivot z row

    const int b = blockIdx.x;
    const int t = threadIdx.x;
    const int lane = t & 63;
    const int w = t >> 6;                   // wave 0..15
    const int wr = w >> 2, wc = w & 3;      // wave grid 4x4 (32x32 tile)
    const int lrow = lane & 15;
    const int lgrp = lane >> 4;

    const float* xb = gx + (size_t)b*NN*NN;
    float* outb = gout + (size_t)b*NN*NN;

    const float bias0 = gb[wc*32 + lrow];
    const float bias1 = gb[wc*32 + 16 + lrow];

    // ---- W -> registers as mm_a B-fragments (k=fi, col=fo) ----
    f16x8 Wh[4][2];
    #pragma unroll
    for (int ks = 0; ks < 4; ++ks)
    #pragma unroll
    for (int ct = 0; ct < 2; ++ct) {
        const int col = wc*32 + ct*16 + lrow;
        #pragma unroll
        for (int r = 0; r < 8; ++r)
            Wh[ks][ct][r] = (f16)gW[(ks*32 + lgrp*8 + r)*NN + col];
    }

    // ---- G = I as A-fragments (rows wr*32+rt*16+lrow, k = ks*32+lgrp*8+e) ----
    f16x8 Gf[4][2];
    #pragma unroll
    for (int ks = 0; ks < 4; ++ks)
    #pragma unroll
    for (int rt = 0; rt < 2; ++rt)
    #pragma unroll
    for (int e = 0; e < 8; ++e)
        Gf[ks][rt][e] = (f16)(((ks*32 + lgrp*8 + e) == (wr*32 + rt*16 + lrow)) ? 1.f : 0.f);

    // ---- init: X = f16(x) row-major, out = eye, d0 = rsqrt(2) ----
    #pragma unroll
    for (int q = 0; q < 16; ++q) {
        int idx = q*1024 + t;
        int r = idx >> 7, c = idx & 127;
        X[r*SP + c] = (f16)xb[idx];
        outb[idx] = (r == c) ? 1.f : 0.f;
    }
    if (t < NN) s_df16[t] = (f16)0.70710678f;
    __syncthreads();

    for (int i = 0; i < NN; ++i) {
        const int pn = i + 1;

        // ================= P1: mm_a + register G-update =================
        // mm_a: u = x_hat . W   (A from X [n][f], B = Wh regs)
        f32x4 acc[2][2];
        #pragma unroll
        for (int rt = 0; rt < 2; ++rt)
        #pragma unroll
        for (int ct = 0; ct < 2; ++ct)
            acc[rt][ct] = (f32x4){0.f,0.f,0.f,0.f};
        #pragma unroll
        for (int ks = 0; ks < 4; ++ks) {
            const int ko = ks*32 + lgrp*8;
            f16x8 A0 = *(const f16x8*)(X + (wr*32 + lrow)*SP + ko);
            f16x8 A1 = *(const f16x8*)(X + (wr*32 + 16 + lrow)*SP + ko);
            acc[0][0] = mm(A0, Wh[ks][0], acc[0][0]);
            acc[0][1] = mm(A0, Wh[ks][1], acc[0][1]);
            acc[1][0] = mm(A1, Wh[ks][0], acc[1][0]);
            acc[1][1] = mm(A1, Wh[ks][1], acc[1][1]);
        }

        // G-update (register-local, overlaps mm_a latency)
        f16x8 dcv[4];
        #pragma unroll
        for (int ks = 0; ks < 4; ++ks)
            dcv[ks] = *(const f16x8*)(s_df16 + ks*32 + lgrp*8);
        f16 drh[2];
        drh[0] = s_df16[wr*32 + lrow];
        drh[1] = s_df16[wr*32 + 16 + lrow];
        f16 grh[2] = {(f16)0.f, (f16)0.f};
        f16x8 giv[4];
        if (i > 0) {
            grh[0] = s_gi[wr*32 + lrow];
            grh[1] = s_gi[wr*32 + 16 + lrow];
            #pragma unroll
            for (int ks = 0; ks < 4; ++ks)
                giv[ks] = *(const f16x8*)(s_gi + ks*32 + lgrp*8);
        }
        float rs[2] = {0.f, 0.f};
        #pragma unroll
        for (int rt = 0; rt < 2; ++rt) {
            const int r = wr*32 + rt*16 + lrow;
            f16x8 drs;
            #pragma unroll
            for (int e = 0; e < 8; ++e) drs[e] = drh[rt];
            #pragma unroll
            for (int ks = 0; ks < 4; ++ks) {
                f16x8 g = Gf[ks][rt];
                #pragma unroll
                for (int e = 0; e < 8; ++e)           // + I (diag)
                    if (ks*32 + lgrp*8 + e == r) g[e] += (f16)1.0f;
                g = g * dcv[ks] * drs;                // d .* (..) .* d
                if (i > 0) {
                    if (ks == (i >> 5)) {             // col-i fix
                        const int es = i & 7;
                        const bool lm = (lgrp == ((i >> 3) & 3));
                        #pragma unroll
                        for (int e = 0; e < 8; ++e)
                            g[e] = (lm && es == e) ? grh[rt] : g[e];
                    }
                    const bool rm = (r == i);         // row-i fix
                    #pragma unroll
                    for (int e = 0; e < 8; ++e)
                        g[e] = rm ? giv[ks][e] : g[e];
                }
                Gf[ks][rt] = g;
                rs[rt] = rowdot8(g, rs[rt]);
            }
            rs[rt] += __shfl_xor(rs[rt], 16);
            rs[rt] += __shfl_xor(rs[rt], 32);
        }
        if (wc == 0 && lgrp == 0) {
            s_rows[wr*32 + lrow]      = rs[0];
            s_rows[wr*32 + 16 + lrow] = rs[1];
        }
        // dump G_i row pn (symmetric: = col pn) for P4
        if (pn < NN && wc == 0 && wr == (pn >> 5)) {
            const int prt = (pn >> 4) & 1;
            if (lrow == (pn & 15)) {
                #pragma unroll
                for (int ks = 0; ks < 4; ++ks) {
                    f16x8 rf;
                    #pragma unroll
                    for (int e = 0; e < 8; ++e)
                        rf[e] = prt ? Gf[ks][1][e] : Gf[ks][0][e];
                    *(f16x8*)(s_rowi + ks*32 + lgrp*8) = rf;
                }
            }
        }
        // u writes: [fo][m] col-major -> contiguous f16x4
        #pragma unroll
        for (int rt = 0; rt < 2; ++rt)
        #pragma unroll
        for (int ct = 0; ct < 2; ++ct) {
            f16x4 uv;
            #pragma unroll
            for (int q = 0; q < 4; ++q) uv[q] = (f16)acc[rt][ct][q];
            *(f16x4*)(U + (wc*32 + ct*16 + lrow)*SP + wr*32 + rt*16 + lgrp*4) = uv;
        }
        __syncthreads();

        // ================= P2: mm_b z = G . u + epilogue =================
        #pragma unroll
        for (int rt = 0; rt < 2; ++rt)
        #pragma unroll
        for (int ct = 0; ct < 2; ++ct)
            acc[rt][ct] = (f32x4){0.f,0.f,0.f,0.f};
        #pragma unroll
        for (int ks = 0; ks < 4; ++ks) {
            const int ko = ks*32 + lgrp*8;
            f16x8 B0 = *(const f16x8*)(U + (wc*32 + lrow)*SP + ko);
            f16x8 B1 = *(const f16x8*)(U + (wc*32 + 16 + lrow)*SP + ko);
            acc[0][0] = mm(Gf[ks][0], B0, acc[0][0]);
            acc[0][1] = mm(Gf[ks][0], B1, acc[0][1]);
            acc[1][0] = mm(Gf[ks][1], B0, acc[1][0]);
            acc[1][1] = mm(Gf[ks][1], B1, acc[1][1]);
        }
        float z[2][2][4];
        #pragma unroll
        for (int rt = 0; rt < 2; ++rt)
        #pragma unroll
        for (int ct = 0; ct < 2; ++ct)
        #pragma unroll
        for (int q = 0; q < 4; ++q)
            z[rt][ct][q] = fmaxf(acc[rt][ct][q] + (ct ? bias1 : bias0), 0.f);
        {
            float ss[8];
            #pragma unroll
            for (int k = 0; k < 8; ++k) {
                float a = z[k>>2][0][k&3], c2 = z[k>>2][1][k&3];
                ss[k] = a*a + c2*c2;
            }
            #pragma unroll
            for (int k = 0; k < 8; ++k) {
                ss[k] += __shfl_xor(ss[k], 1);
                ss[k] += __shfl_xor(ss[k], 2);
                ss[k] += __shfl_xor(ss[k], 4);
                ss[k] += __shfl_xor(ss[k], 8);
            }
            if (lrow == 0) {
                #pragma unroll
                for (int k = 0; k < 8; ++k) {
                    int row = wr*32 + (k>>2)*16 + lgrp*4 + (k&3);
                    s_ssq[wc*NN + row] = ss[k];
                }
            }
        }
        if (pn < NN && wr == (pn >> 5) && lgrp == ((pn >> 2) & 3)) {
            int prt = (pn >> 4) & 1, pq = pn & 3;
            float z0 = prt ? z[1][0][0] : z[0][0][0];   // select frag rt
            float z1 = prt ? z[1][1][0] : z[0][1][0];
            // pq select (0..3), compile-time unrolled compares
            #pragma unroll
            for (int q = 1; q < 4; ++q) {
                z0 = (pq == q) ? (prt ? z[1][0][q] : z[0][0][q]) : z0;
                z1 = (pq == q) ? (prt ? z[1][1][q] : z[0][1][q]) : z1;
            }
            s_zrow[wc*32 + lrow]      = z0;
            s_zrow[wc*32 + 16 + lrow] = z1;
        }
        __syncthreads();

        // ================= P3: normalize -> X, pd partials =================
        {
            float dv[8];
            #pragma unroll
            for (int k = 0; k < 8; ++k) {
                int row = wr*32 + (k>>2)*16 + lgrp*4 + (k&3);
                float sq = s_ssq[row] + s_ssq[NN+row] + s_ssq[2*NN+row] + s_ssq[3*NN+row];
                dv[k] = (i == 0) ? 1.f : 1.f/(sqrtf(sq) + 1e-8f);
            }
            #pragma unroll
            for (int rt = 0; rt < 2; ++rt)
            #pragma unroll
            for (int ct = 0; ct < 2; ++ct) {
                const int col = wc*32 + ct*16 + lrow;
                #pragma unroll
                for (int q = 0; q < 4; ++q)
                    X[(wr*32 + rt*16 + lgrp*4 + q)*SP + col] =
                        (f16)(z[rt][ct][q] * dv[rt*4 + q]);
            }
            float zr0 = s_zrow[wc*32 + lrow];
            float zr1 = s_zrow[wc*32 + 16 + lrow];
            float pd[8];
            #pragma unroll
            for (int k = 0; k < 8; ++k)
                pd[k] = z[k>>2][0][k&3]*zr0 + z[k>>2][1][k&3]*zr1;
            #pragma unroll
            for (int k = 0; k < 8; ++k) {
                pd[k] += __shfl_xor(pd[k], 1);
                pd[k] += __shfl_xor(pd[k], 2);
                pd[k] += __shfl_xor(pd[k], 4);
                pd[k] += __shfl_xor(pd[k], 8);
            }
            if (lrow == 0) {
                #pragma unroll
                for (int k = 0; k < 8; ++k) {
                    int row = wr*32 + (k>>2)*16 + lgrp*4 + (k&3);
                    s_pdt[wc*NN + row] = pd[k];
                }
            }
        }
        __syncthreads();

        // ================= P4 (wave 0): probs, degrees, s_gi, out =========
        if (w == 0 && pn < NN) {
            float pvv[2], rvi[2];
            float sp = 0.f, srlt = 0.f, srall = 0.f;
            float sqp = s_ssq[pn] + s_ssq[NN+pn] + s_ssq[2*NN+pn] + s_ssq[3*NN+pn];
            float dp = (i == 0) ? 1.f : 1.f/(sqrtf(sqp) + 1e-8f);
            #pragma unroll
            for (int h = 0; h < 2; ++h) {
                const int tt = lane + h*64;
                float zd  = s_pdt[tt] + s_pdt[NN+tt] + s_pdt[2*NN+tt] + s_pdt[3*NN+tt];
                float sqj = s_ssq[tt] + s_ssq[NN+tt] + s_ssq[2*NN+tt] + s_ssq[3*NN+tt];
                float dj = (i == 0) ? 1.f : 1.f/(sqrtf(sqj) + 1e-8f);
                float pv = 1.f/(1.f + expf(-0.5f * zd * dj * dp));
                pvv[h] = pv;
                rvi[h] = (float)s_rowi[tt];
                if (tt < pn) {
                    sp += pv; srlt += rvi[h];
                    outb[pn*NN + tt] = pv;
                    outb[tt*NN + pn] = pv;
                }
                srall += rvi[h];
            }
            #pragma unroll
            for (int m2 = 1; m2 < 64; m2 <<= 1) {
                sp    += __shfl_xor(sp, m2);
                srlt  += __shfl_xor(srlt, m2);
                srall += __shfl_xor(srall, m2);
            }
            const float rsm_piv = sp + srall - srlt;   // rowsum(M) at pivot
            const float d_piv = 1.f/sqrtf(rsm_piv + 1.f + 1e-8f);
            #pragma unroll
            for (int h = 0; h < 2; ++h) {
                const int tt = lane + h*64;
                float rsmt = (tt < pn)  ? (s_rows[tt] - rvi[h] + pvv[h])
                           : (tt == pn) ? rsm_piv
                                        : s_rows[tt];
                float dt = 1.f/sqrtf(rsmt + 1.f + 1e-8f);
                s_df16[tt] = (f16)dt;
                float Mv = (tt < pn)  ? pvv[h]
                         : (tt == pn) ? (rvi[h] + 1.f)
                                      : rvi[h];
                s_gi[tt] = (f16)(Mv * d_piv * dt);
            }
        }
        __syncthreads();
    }
}

extern "C" void kernel_launch(void* const* d_in, const int* in_sizes, int n_in,
                              void* d_out, int out_size, void* d_ws, size_t ws_size,
                              hipStream_t stream) {
    const float* x  = (const float*)d_in[0];
    const float* W  = (const float*)d_in[1];
    const float* bb = (const float*)d_in[2];
    float* out = (float*)d_out;

    const size_t shmem = (size_t)(2*NN*SP + 3*NN)*sizeof(f16)
                       + (size_t)(NN + 4*NN + 4*NN + NN)*sizeof(float);
    hipFuncSetAttribute((const void*)gcn_gen_kernel,
                        hipFuncAttributeMaxDynamicSharedMemorySize, (int)shmem);
    gcn_gen_kernel<<<8, 1024, shmem, stream>>>(x, W, bb, out);
}

// Round 6
// 1296.561 us; speedup vs baseline: 1.4168x; 1.4168x over previous
//
#include <hip/hip_runtime.h>
#include <math.h>

// GCN generator: B=8, N=F=128. One block/batch, 1024 threads (16 waves).
// Round 6: z = D(M+I)D u = (D M D)u + d^2 u. G-update fused into mm_b's
// A-fragment path (read frag, pk-mul by dr*dc, MFMA, write own quarter to
// the OTHER G buffer). Patches (row/col i), diagonal track, rowsum finish
// all O(N) in the serial wave. 3 barriers/step:
//   P2: fused mm_b + epilogue   P3: normalize->X + pd
//   P4: mm_a u=x.W -> U (15 waves) || wave0: probs/degrees/patch/diag/out.

#define NN 128
#define SP 136

typedef _Float16 f16;
typedef _Float16 f16x8 __attribute__((ext_vector_type(8)));
typedef _Float16 f16x4 __attribute__((ext_vector_type(4)));
typedef _Float16 f16x2 __attribute__((ext_vector_type(2)));
typedef float f32x4 __attribute__((ext_vector_type(4)));

__device__ __forceinline__ f32x4 mm(f16x8 a, f16x8 b, f32x4 c) {
    return __builtin_amdgcn_mfma_f32_16x16x32_f16(a, b, c, 0, 0, 0);
}

__device__ __forceinline__ float rowdot8(f16x8 g, float acc) {
#if __has_builtin(__builtin_amdgcn_fdot2)
    const f16x2 one2 = {(f16)1.0f, (f16)1.0f};
    #pragma unroll
    for (int p = 0; p < 4; ++p) {
        f16x2 pr = {g[2*p], g[2*p+1]};
        acc = __builtin_amdgcn_fdot2(pr, one2, acc, false);
    }
#else
    #pragma unroll
    for (int e = 0; e < 8; ++e) acc += (float)g[e];
#endif
    return acc;
}

__global__ __launch_bounds__(1024, 4)
void gcn_gen_kernel(const float* __restrict__ gx,
                    const float* __restrict__ gW,
                    const float* __restrict__ gb,
                    float* __restrict__ gout)
{
    extern __shared__ char lds_raw[];
    f16* X     = (f16*)lds_raw;              // [128][136] x-hat [n][f]
    f16* U     = X + NN*SP;                  // [128][136] u = x.W, [fo][m]
    f16* Gb0   = U + NN*SP;                  // [128][136] M-hat ping
    f16* Gb1   = Gb0 + NN*SP;                // [128][136] M-hat pong
    f16* s_df16  = Gb1 + NN*SP;              // [128] d (f16)
    float* s_d    = (float*)(s_df16 + NN);   // [128] d (f32)
    float* s_diag = s_d + NN;                // [128] diag of carried C
    float* s_rows = s_diag + NN;             // [4][128] rowsum quarters
    float* s_ssq  = s_rows + 4*NN;           // [4][128] ssq partials by wc
    float* s_pdt  = s_ssq + 4*NN;            // [4][128] zdot partials by wc
    float* s_zrow = s_pdt + 4*NN;            // [128] pivot z row

    const int b = blockIdx.x;
    const int t = threadIdx.x;
    const int lane = t & 63;
    const int w = t >> 6;
    const int wr = w >> 2, wc = w & 3;       // wave grid 4x4 (32x32 tile)
    const int lrow = lane & 15;
    const int lgrp = lane >> 4;

    const float* xb = gx + (size_t)b*NN*NN;
    float* outb = gout + (size_t)b*NN*NN;

    const float bias0 = gb[wc*32 + lrow];
    const float bias1 = gb[wc*32 + 16 + lrow];

    // ---- W -> registers as B-fragments for mm_a (k=fi, col=fo) ----
    f16x8 Wh[4][2];
    #pragma unroll
    for (int ks = 0; ks < 4; ++ks)
    #pragma unroll
    for (int ct = 0; ct < 2; ++ct) {
        const int col = wc*32 + ct*16 + lrow;
        #pragma unroll
        for (int r = 0; r < 8; ++r)
            Wh[ks][ct][r] = (f16)gW[(ks*32 + lgrp*8 + r)*NN + col];
    }

    // ---- init: X = f16(x), G0 = I(raw), out = eye, vectors ----
    #pragma unroll
    for (int q = 0; q < 16; ++q) {
        int idx = q*1024 + t;
        int r = idx >> 7, c = idx & 127;
        float e = (r == c) ? 1.f : 0.f;
        X[r*SP + c] = (f16)xb[idx];
        Gb0[r*SP + c] = (f16)e;
        outb[idx] = e;
    }
    if (t < NN) {
        s_d[t] = 0.70710678f;        // d for step 0 (deg = 2)
        s_df16[t] = (f16)0.70710678f;
        s_diag[t] = 1.f;             // diag(C_0) = 1
    }
    __syncthreads();

    // mm_a: u = x_hat . W  -> U[fo][m]
    auto run_mma = [&]() {
        f32x4 a2[2][2];
        #pragma unroll
        for (int rt = 0; rt < 2; ++rt)
        #pragma unroll
        for (int ct = 0; ct < 2; ++ct)
            a2[rt][ct] = (f32x4){0.f,0.f,0.f,0.f};
        #pragma unroll
        for (int ks = 0; ks < 4; ++ks) {
            const int ko = ks*32 + lgrp*8;
            f16x8 A0 = *(const f16x8*)(X + (wr*32 + lrow)*SP + ko);
            f16x8 A1 = *(const f16x8*)(X + (wr*32 + 16 + lrow)*SP + ko);
            a2[0][0] = mm(A0, Wh[ks][0], a2[0][0]);
            a2[0][1] = mm(A0, Wh[ks][1], a2[0][1]);
            a2[1][0] = mm(A1, Wh[ks][0], a2[1][0]);
            a2[1][1] = mm(A1, Wh[ks][1], a2[1][1]);
        }
        #pragma unroll
        for (int rt = 0; rt < 2; ++rt)
        #pragma unroll
        for (int ct = 0; ct < 2; ++ct) {
            f16x4 uv;
            #pragma unroll
            for (int q = 0; q < 4; ++q) uv[q] = (f16)a2[rt][ct][q];
            *(f16x4*)(U + (wc*32 + ct*16 + lrow)*SP + wr*32 + rt*16 + lgrp*4) = uv;
        }
    };
    run_mma();
    __syncthreads();

    for (int i = 0; i < NN; ++i) {
        const int pn = i + 1;
        f16* Gc = (i & 1) ? Gb1 : Gb0;       // holds M-hat (patched C_{i-1})
        f16* Gn = (i & 1) ? Gb0 : Gb1;       // receives scaled carry C_i

        // ========== P2: z = (D M D) u + d^2 u, fused update ==========
        f16x8 dcv[4];
        #pragma unroll
        for (int ks = 0; ks < 4; ++ks)
            dcv[ks] = *(const f16x8*)(s_df16 + ks*32 + lgrp*8);
        const f16 drh0 = s_df16[wr*32 + lrow];
        const f16 drh1 = s_df16[wr*32 + 16 + lrow];

        f32x4 acc[2][2];
        #pragma unroll
        for (int rt = 0; rt < 2; ++rt)
        #pragma unroll
        for (int ct = 0; ct < 2; ++ct)
            acc[rt][ct] = (f32x4){0.f,0.f,0.f,0.f};
        float rs0 = 0.f, rs1 = 0.f;
        #pragma unroll
        for (int ks = 0; ks < 4; ++ks) {
            const int ko = ks*32 + lgrp*8;
            f16x8 B0 = *(const f16x8*)(U + (wc*32 + lrow)*SP + ko);
            f16x8 B1 = *(const f16x8*)(U + (wc*32 + 16 + lrow)*SP + ko);
            f16x8 A0 = *(const f16x8*)(Gc + (wr*32 + lrow)*SP + ko);
            f16x8 A1 = *(const f16x8*)(Gc + (wr*32 + 16 + lrow)*SP + ko);
            f16x8 G0s = A0 * dcv[ks] * drh0;
            f16x8 G1s = A1 * dcv[ks] * drh1;
            acc[0][0] = mm(G0s, B0, acc[0][0]);
            acc[0][1] = mm(G0s, B1, acc[0][1]);
            acc[1][0] = mm(G1s, B0, acc[1][0]);
            acc[1][1] = mm(G1s, B1, acc[1][1]);
            if (ks == wc) {                   // own quarter: carry + rowsum
                *(f16x8*)(Gn + (wr*32 + lrow)*SP + ko) = G0s;
                *(f16x8*)(Gn + (wr*32 + 16 + lrow)*SP + ko) = G1s;
                rs0 = rowdot8(G0s, rs0);
                rs1 = rowdot8(G1s, rs1);
            }
        }
        rs0 += __shfl_xor(rs0, 16); rs0 += __shfl_xor(rs0, 32);
        rs1 += __shfl_xor(rs1, 16); rs1 += __shfl_xor(rs1, 32);
        if (lgrp == 0) {
            s_rows[wc*NN + wr*32 + lrow]      = rs0;
            s_rows[wc*NN + wr*32 + 16 + lrow] = rs1;
        }

        // z = acc + d_r^2 * u_rc + bias, relu
        const float4 dr4a = *(const float4*)(s_d + wr*32 + lgrp*4);
        const float4 dr4b = *(const float4*)(s_d + wr*32 + 16 + lgrp*4);
        float z[2][2][4];
        #pragma unroll
        for (int rt = 0; rt < 2; ++rt)
        #pragma unroll
        for (int ct = 0; ct < 2; ++ct) {
            f16x4 u4 = *(const f16x4*)(U + (wc*32 + ct*16 + lrow)*SP
                                         + wr*32 + rt*16 + lgrp*4);
            #pragma unroll
            for (int q = 0; q < 4; ++q) {
                float dq = rt ? ((const float*)&dr4b)[q] : ((const float*)&dr4a)[q];
                z[rt][ct][q] = fmaxf(acc[rt][ct][q] + dq*dq*(float)u4[q]
                                     + (ct ? bias1 : bias0), 0.f);
            }
        }
        {
            float ss[8];
            #pragma unroll
            for (int k = 0; k < 8; ++k) {
                float a = z[k>>2][0][k&3], c2 = z[k>>2][1][k&3];
                ss[k] = a*a + c2*c2;
            }
            #pragma unroll
            for (int k = 0; k < 8; ++k) {
                ss[k] += __shfl_xor(ss[k], 1);
                ss[k] += __shfl_xor(ss[k], 2);
                ss[k] += __shfl_xor(ss[k], 4);
                ss[k] += __shfl_xor(ss[k], 8);
            }
            if (lrow == 0) {
                #pragma unroll
                for (int k = 0; k < 8; ++k) {
                    int row = wr*32 + (k>>2)*16 + lgrp*4 + (k&3);
                    s_ssq[wc*NN + row] = ss[k];
                }
            }
        }
        if (pn < NN && wr == (pn >> 5) && lgrp == ((pn >> 2) & 3)) {
            const int prt = (pn >> 4) & 1, pq = pn & 3;
            float z0 = prt ? z[1][0][0] : z[0][0][0];
            float z1 = prt ? z[1][1][0] : z[0][1][0];
            #pragma unroll
            for (int q = 1; q < 4; ++q) {
                z0 = (pq == q) ? (prt ? z[1][0][q] : z[0][0][q]) : z0;
                z1 = (pq == q) ? (prt ? z[1][1][q] : z[0][1][q]) : z1;
            }
            s_zrow[wc*32 + lrow]      = z0;
            s_zrow[wc*32 + 16 + lrow] = z1;
        }
        __syncthreads();

        // ========== P3: normalize -> X, pd partials ==========
        {
            float dv[8];
            #pragma unroll
            for (int rt = 0; rt < 2; ++rt) {
                float4 s0 = *(const float4*)(s_ssq          + wr*32 + rt*16 + lgrp*4);
                float4 s1 = *(const float4*)(s_ssq +   NN   + wr*32 + rt*16 + lgrp*4);
                float4 s2 = *(const float4*)(s_ssq + 2*NN   + wr*32 + rt*16 + lgrp*4);
                float4 s3 = *(const float4*)(s_ssq + 3*NN   + wr*32 + rt*16 + lgrp*4);
                #pragma unroll
                for (int q = 0; q < 4; ++q) {
                    float sq = ((const float*)&s0)[q] + ((const float*)&s1)[q]
                             + ((const float*)&s2)[q] + ((const float*)&s3)[q];
                    dv[rt*4 + q] = (i == 0) ? 1.f : 1.f/(sqrtf(sq) + 1e-8f);
                }
            }
            #pragma unroll
            for (int rt = 0; rt < 2; ++rt)
            #pragma unroll
            for (int ct = 0; ct < 2; ++ct) {
                const int col = wc*32 + ct*16 + lrow;
                #pragma unroll
                for (int q = 0; q < 4; ++q)
                    X[(wr*32 + rt*16 + lgrp*4 + q)*SP + col] =
                        (f16)(z[rt][ct][q] * dv[rt*4 + q]);
            }
            float zr0 = s_zrow[wc*32 + lrow];
            float zr1 = s_zrow[wc*32 + 16 + lrow];
            float pd[8];
            #pragma unroll
            for (int k = 0; k < 8; ++k)
                pd[k] = z[k>>2][0][k&3]*zr0 + z[k>>2][1][k&3]*zr1;
            #pragma unroll
            for (int k = 0; k < 8; ++k) {
                pd[k] += __shfl_xor(pd[k], 1);
                pd[k] += __shfl_xor(pd[k], 2);
                pd[k] += __shfl_xor(pd[k], 4);
                pd[k] += __shfl_xor(pd[k], 8);
            }
            if (lrow == 0) {
                #pragma unroll
                for (int k = 0; k < 8; ++k) {
                    int row = wr*32 + (k>>2)*16 + lgrp*4 + (k&3);
                    s_pdt[wc*NN + row] = pd[k];
                }
            }
        }
        __syncthreads();

        // ========== P4: mm_a (all waves) || wave0 serial ==========
        if (pn < NN) {
            run_mma();
            if (w == 0) {
                float sqp = s_ssq[pn] + s_ssq[NN+pn] + s_ssq[2*NN+pn] + s_ssq[3*NN+pn];
                float dp = (i == 0) ? 1.f : 1.f/(sqrtf(sqp) + 1e-8f);
                float pv[2], rsC[2];
                float sp = 0.f;
                #pragma unroll
                for (int h = 0; h < 2; ++h) {
                    const int tt = lane + h*64;
                    float zd  = s_pdt[tt] + s_pdt[NN+tt] + s_pdt[2*NN+tt] + s_pdt[3*NN+tt];
                    float sqj = s_ssq[tt] + s_ssq[NN+tt] + s_ssq[2*NN+tt] + s_ssq[3*NN+tt];
                    float dj = (i == 0) ? 1.f : 1.f/(sqrtf(sqj) + 1e-8f);
                    float p = 1.f/(1.f + expf(-0.5f*zd*dj*dp));
                    pv[h] = p;
                    float dold = s_d[tt];
                    rsC[h] = s_rows[tt] + s_rows[NN+tt] + s_rows[2*NN+tt] + s_rows[3*NN+tt]
                           + dold*dold;                   // rowsum(C_i)_t
                    if (tt < pn) {
                        sp += p;
                        outb[pn*NN + tt] = p;
                        outb[tt*NN + pn] = p;
                    }
                }
                #pragma unroll
                for (int m2 = 1; m2 < 64; m2 <<= 1) sp += __shfl_xor(sp, m2);
                #pragma unroll
                for (int h = 0; h < 2; ++h) {
                    const int tt = lane + h*64;
                    float dgC = s_diag[tt];                // diag(C_i)_t
                    float rsM = (tt < pn) ? (rsC[h] + pv[h])
                              : ((tt == pn) ? (sp + dgC) : rsC[h]);
                    float dnew = 1.f/sqrtf(rsM + 1.f + 1e-8f);
                    s_d[tt] = dnew;
                    s_df16[tt] = (f16)dnew;
                    s_diag[tt] = dnew*dnew*(dgC + 1.f);    // diag(C_{i+1})
                    Gn[tt*SP + tt] = (f16)dgC;             // fix stored diag
                    if (tt < pn) {                         // patch row/col pn
                        f16 pf = (f16)pv[h];
                        Gn[pn*SP + tt] = pf;
                        Gn[tt*SP + pn] = pf;
                    }
                }
            }
        }
        __syncthreads();
    }
}

extern "C" void kernel_launch(void* const* d_in, const int* in_sizes, int n_in,
                              void* d_out, int out_size, void* d_ws, size_t ws_size,
                              hipStream_t stream) {
    const float* x  = (const float*)d_in[0];
    const float* W  = (const float*)d_in[1];
    const float* bb = (const float*)d_in[2];
    float* out = (float*)d_out;

    const size_t shmem = (size_t)(4*NN*SP + NN)*sizeof(f16)
                       + (size_t)(2*NN + 4*NN + 4*NN + 4*NN + NN)*sizeof(float);
    hipFuncSetAttribute((const void*)gcn_gen_kernel,
                        hipFuncAttributeMaxDynamicSharedMemorySize, (int)shmem);
    gcn_gen_kernel<<<8, 1024, shmem, stream>>>(x, W, bb, out);
}

// Round 7
// 926.468 us; speedup vs baseline: 1.9828x; 1.3995x over previous
//
#include <hip/hip_runtime.h>
#include <math.h>

// GCN generator: B=8, N=F=128. One block/batch, 1024 threads (16 waves).
// Round 7: 2 barriers/step. Row-normalize folded into mm_a's A-scale
// (X holds UNNORMALIZED z); pd dots done by the serial wave directly.
//   P2: z=(D M D)u + d^2 u fused update + relu + ssq + z->X
//   P4: mm_a u=(dv.z).W -> U (all waves) || wave0: pd/probs/degrees/patches.

#define NN 128
#define SP 136

typedef _Float16 f16;
typedef _Float16 f16x8 __attribute__((ext_vector_type(8)));
typedef _Float16 f16x4 __attribute__((ext_vector_type(4)));
typedef _Float16 f16x2 __attribute__((ext_vector_type(2)));
typedef float f32x4 __attribute__((ext_vector_type(4)));

__device__ __forceinline__ f32x4 mm(f16x8 a, f16x8 b, f32x4 c) {
    return __builtin_amdgcn_mfma_f32_16x16x32_f16(a, b, c, 0, 0, 0);
}

__device__ __forceinline__ float rowdot8(f16x8 g, float acc) {
#if __has_builtin(__builtin_amdgcn_fdot2)
    const f16x2 one2 = {(f16)1.0f, (f16)1.0f};
    #pragma unroll
    for (int p = 0; p < 4; ++p) {
        f16x2 pr = {g[2*p], g[2*p+1]};
        acc = __builtin_amdgcn_fdot2(pr, one2, acc, false);
    }
#else
    #pragma unroll
    for (int e = 0; e < 8; ++e) acc += (float)g[e];
#endif
    return acc;
}

__device__ __forceinline__ float dot8(f16x8 a, f16x8 b, float acc) {
#if __has_builtin(__builtin_amdgcn_fdot2)
    #pragma unroll
    for (int p = 0; p < 4; ++p) {
        f16x2 pa = {a[2*p], a[2*p+1]};
        f16x2 pb = {b[2*p], b[2*p+1]};
        acc = __builtin_amdgcn_fdot2(pa, pb, acc, false);
    }
#else
    #pragma unroll
    for (int e = 0; e < 8; ++e) acc += (float)a[e]*(float)b[e];
#endif
    return acc;
}

__global__ __launch_bounds__(1024, 4)
void gcn_gen_kernel(const float* __restrict__ gx,
                    const float* __restrict__ gW,
                    const float* __restrict__ gb,
                    float* __restrict__ gout)
{
    extern __shared__ char lds_raw[];
    f16* X     = (f16*)lds_raw;              // [128][136] UNNORM z [n][f]
    f16* U     = X + NN*SP;                  // [128][136] u = x_hat.W, [fo][m]
    f16* Gb0   = U + NN*SP;                  // [128][136] M-hat ping
    f16* Gb1   = Gb0 + NN*SP;                // [128][136] M-hat pong
    f16* s_df16  = Gb1 + NN*SP;              // [128] d (f16)
    float* s_d    = (float*)(s_df16 + NN);   // [128] d (f32)
    float* s_diag = s_d + NN;                // [128] diag of carried C
    float* s_rows = s_diag + NN;             // [4][128] rowsum quarters
    float* s_ssq  = s_rows + 4*NN;           // [4][128] ssq partials by wc

    const int b = blockIdx.x;
    const int t = threadIdx.x;
    const int lane = t & 63;
    const int w = t >> 6;
    const int wr = w >> 2, wc = w & 3;       // wave grid 4x4 (32x32 tile)
    const int lrow = lane & 15;
    const int lgrp = lane >> 4;

    const float* xb = gx + (size_t)b*NN*NN;
    float* outb = gout + (size_t)b*NN*NN;

    const float bias0 = gb[wc*32 + lrow];
    const float bias1 = gb[wc*32 + 16 + lrow];

    // ---- W -> registers as B-fragments for mm_a (k=fi, col=fo) ----
    f16x8 Wh[4][2];
    #pragma unroll
    for (int ks = 0; ks < 4; ++ks)
    #pragma unroll
    for (int ct = 0; ct < 2; ++ct) {
        const int col = wc*32 + ct*16 + lrow;
        #pragma unroll
        for (int r = 0; r < 8; ++r)
            Wh[ks][ct][r] = (f16)gW[(ks*32 + lgrp*8 + r)*NN + col];
    }

    // ---- init: X = f16(x), G0 = I(raw), out = eye, vectors ----
    #pragma unroll
    for (int q = 0; q < 16; ++q) {
        int idx = q*1024 + t;
        int r = idx >> 7, c = idx & 127;
        float e = (r == c) ? 1.f : 0.f;
        X[r*SP + c] = (f16)xb[idx];
        Gb0[r*SP + c] = (f16)e;
        outb[idx] = e;
    }
    if (t < NN) {
        s_d[t] = 0.70710678f;
        s_df16[t] = (f16)0.70710678f;
        s_diag[t] = 1.f;
    }
    __syncthreads();

    // mm_a: u = (sv . X) . W  -> U[fo][m]  (sv = per-row scale, f16)
    auto run_mma = [&](f16 sv0, f16 sv1) {
        f32x4 a2[2][2];
        #pragma unroll
        for (int rt = 0; rt < 2; ++rt)
        #pragma unroll
        for (int ct = 0; ct < 2; ++ct)
            a2[rt][ct] = (f32x4){0.f,0.f,0.f,0.f};
        #pragma unroll
        for (int ks = 0; ks < 4; ++ks) {
            const int ko = ks*32 + lgrp*8;
            f16x8 A0 = *(const f16x8*)(X + (wr*32 + lrow)*SP + ko) * sv0;
            f16x8 A1 = *(const f16x8*)(X + (wr*32 + 16 + lrow)*SP + ko) * sv1;
            a2[0][0] = mm(A0, Wh[ks][0], a2[0][0]);
            a2[0][1] = mm(A0, Wh[ks][1], a2[0][1]);
            a2[1][0] = mm(A1, Wh[ks][0], a2[1][0]);
            a2[1][1] = mm(A1, Wh[ks][1], a2[1][1]);
        }
        #pragma unroll
        for (int rt = 0; rt < 2; ++rt)
        #pragma unroll
        for (int ct = 0; ct < 2; ++ct) {
            f16x4 uv;
            #pragma unroll
            for (int q = 0; q < 4; ++q) uv[q] = (f16)a2[rt][ct][q];
            *(f16x4*)(U + (wc*32 + ct*16 + lrow)*SP + wr*32 + rt*16 + lgrp*4) = uv;
        }
    };
    run_mma((f16)1.0f, (f16)1.0f);
    __syncthreads();

    for (int i = 0; i < NN; ++i) {
        const int pn = i + 1;
        f16* Gc = (i & 1) ? Gb1 : Gb0;       // M-hat (patched C_{i-1})
        f16* Gn = (i & 1) ? Gb0 : Gb1;       // receives scaled carry C_i

        // ========== P2: z = (D M D) u + d^2 u, fused update ==========
        f16x8 dcv[4];
        #pragma unroll
        for (int ks = 0; ks < 4; ++ks)
            dcv[ks] = *(const f16x8*)(s_df16 + ks*32 + lgrp*8);
        const f16 drh0 = s_df16[wr*32 + lrow];
        const f16 drh1 = s_df16[wr*32 + 16 + lrow];

        f32x4 acc[2][2];
        #pragma unroll
        for (int rt = 0; rt < 2; ++rt)
        #pragma unroll
        for (int ct = 0; ct < 2; ++ct)
            acc[rt][ct] = (f32x4){0.f,0.f,0.f,0.f};
        float rs0 = 0.f, rs1 = 0.f;
        #pragma unroll
        for (int ks = 0; ks < 4; ++ks) {
            const int ko = ks*32 + lgrp*8;
            f16x8 B0 = *(const f16x8*)(U + (wc*32 + lrow)*SP + ko);
            f16x8 B1 = *(const f16x8*)(U + (wc*32 + 16 + lrow)*SP + ko);
            f16x8 A0 = *(const f16x8*)(Gc + (wr*32 + lrow)*SP + ko);
            f16x8 A1 = *(const f16x8*)(Gc + (wr*32 + 16 + lrow)*SP + ko);
            f16x8 G0s = A0 * dcv[ks] * drh0;
            f16x8 G1s = A1 * dcv[ks] * drh1;
            acc[0][0] = mm(G0s, B0, acc[0][0]);
            acc[0][1] = mm(G0s, B1, acc[0][1]);
            acc[1][0] = mm(G1s, B0, acc[1][0]);
            acc[1][1] = mm(G1s, B1, acc[1][1]);
            if (ks == wc) {                   // own quarter: carry + rowsum
                *(f16x8*)(Gn + (wr*32 + lrow)*SP + ko) = G0s;
                *(f16x8*)(Gn + (wr*32 + 16 + lrow)*SP + ko) = G1s;
                rs0 = rowdot8(G0s, rs0);
                rs1 = rowdot8(G1s, rs1);
            }
        }
        rs0 += __shfl_xor(rs0, 16); rs0 += __shfl_xor(rs0, 32);
        rs1 += __shfl_xor(rs1, 16); rs1 += __shfl_xor(rs1, 32);
        if (lgrp == 0) {
            s_rows[wc*NN + wr*32 + lrow]      = rs0;
            s_rows[wc*NN + wr*32 + 16 + lrow] = rs1;
        }

        // z = acc + d_r^2 * u_rc + bias, relu; store UNNORM z -> X
        const float4 dr4a = *(const float4*)(s_d + wr*32 + lgrp*4);
        const float4 dr4b = *(const float4*)(s_d + wr*32 + 16 + lgrp*4);
        float z[2][2][4];
        #pragma unroll
        for (int rt = 0; rt < 2; ++rt)
        #pragma unroll
        for (int ct = 0; ct < 2; ++ct) {
            f16x4 u4 = *(const f16x4*)(U + (wc*32 + ct*16 + lrow)*SP
                                         + wr*32 + rt*16 + lgrp*4);
            const int col = wc*32 + ct*16 + lrow;
            #pragma unroll
            for (int q = 0; q < 4; ++q) {
                float dq = rt ? ((const float*)&dr4b)[q] : ((const float*)&dr4a)[q];
                float zv = fmaxf(acc[rt][ct][q] + dq*dq*(float)u4[q]
                                 + (ct ? bias1 : bias0), 0.f);
                z[rt][ct][q] = zv;
                X[(wr*32 + rt*16 + lgrp*4 + q)*SP + col] = (f16)zv;
            }
        }
        {
            float ss[8];
            #pragma unroll
            for (int k = 0; k < 8; ++k) {
                float a = z[k>>2][0][k&3], c2 = z[k>>2][1][k&3];
                ss[k] = a*a + c2*c2;
            }
            #pragma unroll
            for (int k = 0; k < 8; ++k) {
                ss[k] += __shfl_xor(ss[k], 1);
                ss[k] += __shfl_xor(ss[k], 2);
                ss[k] += __shfl_xor(ss[k], 4);
                ss[k] += __shfl_xor(ss[k], 8);
            }
            if (lrow == 0) {
                #pragma unroll
                for (int k = 0; k < 8; ++k) {
                    int row = wr*32 + (k>>2)*16 + lgrp*4 + (k&3);
                    s_ssq[wc*NN + row] = ss[k];
                }
            }
        }
        __syncthreads();

        // ========== P4: mm_a (dv-scaled) || wave0 serial ==========
        if (pn < NN) {
            f16 dvh[2];
            #pragma unroll
            for (int rt = 0; rt < 2; ++rt) {
                const int row = wr*32 + rt*16 + lrow;
                float sq = s_ssq[row] + s_ssq[NN+row] + s_ssq[2*NN+row] + s_ssq[3*NN+row];
                float dv = (i == 0) ? 1.f : 1.f/(sqrtf(sq) + 1e-8f);
                dvh[rt] = (f16)fminf(dv, 60000.f);
            }
            run_mma(dvh[0], dvh[1]);

            if (w == 0) {
                float sqp = s_ssq[pn] + s_ssq[NN+pn] + s_ssq[2*NN+pn] + s_ssq[3*NN+pn];
                float dp = (i == 0) ? 1.f : 1.f/(sqrtf(sqp) + 1e-8f);
                float pv[2], rsC[2];
                float sp = 0.f;
                #pragma unroll
                for (int h = 0; h < 2; ++h) {
                    const int tt = lane + h*64;
                    float p = 0.f;
                    if (tt < pn) {
                        const f16* Xr = X + tt*SP;
                        const f16* Xp = X + pn*SP;
                        float a0 = 0.f, a1 = 0.f, a2 = 0.f, a3 = 0.f;
                        #pragma unroll
                        for (int c = 0; c < 4; ++c) {
                            a0 = dot8(*(const f16x8*)(Xr + c*32),
                                      *(const f16x8*)(Xp + c*32), a0);
                            a1 = dot8(*(const f16x8*)(Xr + c*32 + 8),
                                      *(const f16x8*)(Xp + c*32 + 8), a1);
                            a2 = dot8(*(const f16x8*)(Xr + c*32 + 16),
                                      *(const f16x8*)(Xp + c*32 + 16), a2);
                            a3 = dot8(*(const f16x8*)(Xr + c*32 + 24),
                                      *(const f16x8*)(Xp + c*32 + 24), a3);
                        }
                        float zd = (a0 + a1) + (a2 + a3);
                        float sqj = s_ssq[tt] + s_ssq[NN+tt] + s_ssq[2*NN+tt] + s_ssq[3*NN+tt];
                        float dj = (i == 0) ? 1.f : 1.f/(sqrtf(sqj) + 1e-8f);
                        p = 1.f/(1.f + expf(-0.5f*zd*dj*dp));
                        sp += p;
                        outb[pn*NN + tt] = p;
                        outb[tt*NN + pn] = p;
                    }
                    pv[h] = p;
                    float dold = s_d[tt];
                    rsC[h] = s_rows[tt] + s_rows[NN+tt] + s_rows[2*NN+tt] + s_rows[3*NN+tt]
                           + dold*dold;                   // rowsum(C_i)_t
                }
                #pragma unroll
                for (int m2 = 1; m2 < 64; m2 <<= 1) sp += __shfl_xor(sp, m2);
                #pragma unroll
                for (int h = 0; h < 2; ++h) {
                    const int tt = lane + h*64;
                    float dgC = s_diag[tt];                // diag(C_i)_t
                    float rsM = (tt < pn) ? (rsC[h] + pv[h])
                              : ((tt == pn) ? (sp + dgC) : rsC[h]);
                    float dnew = 1.f/sqrtf(rsM + 1.f + 1e-8f);
                    s_d[tt] = dnew;
                    s_df16[tt] = (f16)dnew;
                    s_diag[tt] = dnew*dnew*(dgC + 1.f);    // diag(C_{i+1})
                    Gn[tt*SP + tt] = (f16)dgC;             // fix stored diag
                    if (tt < pn) {                         // patch row/col pn
                        f16 pf = (f16)pv[h];
                        Gn[pn*SP + tt] = pf;
                        Gn[tt*SP + pn] = pf;
                    }
                }
            }
        }
        __syncthreads();
    }
}

extern "C" void kernel_launch(void* const* d_in, const int* in_sizes, int n_in,
                              void* d_out, int out_size, void* d_ws, size_t ws_size,
                              hipStream_t stream) {
    const float* x  = (const float*)d_in[0];
    const float* W  = (const float*)d_in[1];
    const float* bb = (const float*)d_in[2];
    float* out = (float*)d_out;

    const size_t shmem = (size_t)(4*NN*SP + NN)*sizeof(f16)
                       + (size_t)(2*NN + 4*NN + 4*NN)*sizeof(float);
    hipFuncSetAttribute((const void*)gcn_gen_kernel,
                        hipFuncAttributeMaxDynamicSharedMemorySize, (int)shmem);
    gcn_gen_kernel<<<8, 1024, shmem, stream>>>(x, W, bb, out);
}